// Round 5
// baseline (5185.367 us; speedup 1.0000x reference)
//
#include <hip/hip_runtime.h>
#include <hip/hip_cooperative_groups.h>
#include <math.h>

namespace cg = cooperative_groups;

#define BATCH 256
#define DIN 512
#define DFEAT 512
#define HSZ 512
#define VOCAB 32000
#define EMB 64
#define SLEN 16
#define NTILE 250          // VOCAB / 128
#define NJOBS (4 * NTILE)  // 64-row batch tiles x 128-col vocab tiles
#define MARGIN 0.0625f

typedef __attribute__((ext_vector_type(8))) short bf16x8;
typedef __attribute__((ext_vector_type(4))) float f32x4;

__device__ inline unsigned bf16_rne(float x) {
    union { float f; unsigned u; } u; u.f = x;
    unsigned r = u.u + 0x7fff + ((u.u >> 16) & 1);
    return r >> 16;
}

// ---------- fp32 SMEM GEMM (prologue + fallback): C = A @ W^T (+bias) ----------
template<int BM, int BN, int BK, int TM, int TN>
__global__ __launch_bounds__(256) void gemm_atb(
    const float* __restrict__ A,
    const float* __restrict__ W,
    const float* __restrict__ bias,
    float* __restrict__ C, long long ldc,
    int M, int N, int K)
{
    __shared__ float As[BK][BM + 4];
    __shared__ float Bs[BK][BN + 4];
    constexpr int THREADS = (BM / TM) * (BN / TN);
    const int tid = threadIdx.x;
    const int tx = tid % (BN / TN);
    const int ty = tid / (BN / TN);
    const int row0 = blockIdx.y * BM;
    const int col0 = blockIdx.x * BN;
    float acc[TM][TN] = {};
    for (int k0 = 0; k0 < K; k0 += BK) {
        for (int i = tid; i < BM * BK; i += THREADS) {
            int m = i / BK, k = i % BK;
            As[k][m] = A[(long long)(row0 + m) * K + k0 + k];
        }
        for (int i = tid; i < BN * BK; i += THREADS) {
            int n = i / BK, k = i % BK;
            Bs[k][n] = W[(long long)(col0 + n) * K + k0 + k];
        }
        __syncthreads();
        #pragma unroll
        for (int kk = 0; kk < BK; ++kk) {
            float a[TM], b[TN];
            #pragma unroll
            for (int i = 0; i < TM; ++i) a[i] = As[kk][ty * TM + i];
            #pragma unroll
            for (int j = 0; j < TN; ++j) b[j] = Bs[kk][tx * TN + j];
            #pragma unroll
            for (int i = 0; i < TM; ++i)
                #pragma unroll
                for (int j = 0; j < TN; ++j)
                    acc[i][j] = fmaf(a[i], b[j], acc[i][j]);
        }
        __syncthreads();
    }
    #pragma unroll
    for (int i = 0; i < TM; ++i) {
        long long m = row0 + ty * TM + i;
        float* crow = C + m * ldc;
        #pragma unroll
        for (int j = 0; j < TN; ++j) {
            int n = col0 + tx * TN + j;
            float v = acc[i][j];
            if (bias) v += bias[n];
            crow[n] = v;
        }
    }
}

// ---------- fused prologue: Wb cast, Wcat2/bcat2 build (interleaved j*4+comp), sos -> AcatA ----------
__global__ void prep_kernel(const float* __restrict__ out_W, ushort* __restrict__ Wb,
                            const float* __restrict__ W_ih, const float* __restrict__ W_hh,
                            const float* __restrict__ b_ih, const float* __restrict__ b_hh,
                            float* __restrict__ Wcat2, float* __restrict__ bcat2,
                            const float* __restrict__ sos, float* __restrict__ AcatA)
{
    const int stride = gridDim.x * 256;
    const int t0 = blockIdx.x * 256 + threadIdx.x;
    for (int i = t0; i < VOCAB * HSZ / 4; i += stride) {
        const float4 v = ((const float4*)out_W)[i];
        ushort4 o;
        o.x = (ushort)bf16_rne(v.x); o.y = (ushort)bf16_rne(v.y);
        o.z = (ushort)bf16_rne(v.z); o.w = (ushort)bf16_rne(v.w);
        ((ushort4*)Wb)[i] = o;
    }
    for (long long i = t0; i < 2048LL * 576; i += stride) {
        int g = (int)(i / 576), k = (int)(i % 576);
        int j = g >> 2, comp = g & 3;
        float v;
        if (comp == 0)      v = (k < 64) ? W_ih[j * 64 + k]          : W_hh[(long long)j * 512 + k - 64];
        else if (comp == 1) v = (k < 64) ? W_ih[(512 + j) * 64 + k]  : W_hh[(long long)(512 + j) * 512 + k - 64];
        else if (comp == 2) v = (k < 64) ? W_ih[(1024 + j) * 64 + k] : 0.f;
        else                v = (k < 64) ? 0.f                        : W_hh[(long long)(1024 + j) * 512 + k - 64];
        Wcat2[i] = v;
    }
    for (int i = t0; i < 2048; i += stride) {
        int j = i >> 2, comp = i & 3;
        float bv = (comp == 0) ? b_ih[j] + b_hh[j]
                 : (comp == 1) ? b_ih[512 + j] + b_hh[512 + j]
                 : (comp == 2) ? b_ih[1024 + j] : b_hh[1024 + j];
        bcat2[i] = bv;
    }
    for (int i = t0; i < BATCH * EMB; i += stride) {
        AcatA[(long long)(i >> 6) * 576 + (i & 63)] = sos[i & 63];
    }
}

// ================= shared phase bodies (used by mega kernel AND fallback kernels) =================

struct AmaxSh {
    float red[256];
    int qt[32];
    int cand[32];
    float rv[32];
    int cnt2[2];
    int sym;
};

// ---- phase G: fused gcat GEMM (LDS) + GRU gates. blk in [0,256) ----
__device__ __forceinline__ void phaseG(int blk,
    const float* __restrict__ Ar, float* __restrict__ Aw,
    const float* __restrict__ Wcat2, const float* __restrict__ bcat2,
    ushort* __restrict__ hbf, char* smem)
{
    const int tid = threadIdx.x;
    const int ty = blk >> 5;            // batch group (32 rows)
    const int tx = blk & 31;            // col group (64 interleaved cols = 16 j)
    float* As = (float*)smem;                    // [64][34]
    float* Bs = (float*)(smem + 8704);           // [64][68]
    const int tyt = tid >> 4;           // 2 batch rows
    const int txt = tid & 15;           // 4 cols
    float acc[2][4] = {};
    for (int k0 = 0; k0 < 576; k0 += 64) {
        for (int i = tid; i < 32 * 64; i += 256) {
            int m = i >> 6, k = i & 63;
            As[k * 34 + m] = Ar[(long long)(ty * 32 + m) * 576 + k0 + k];
        }
        for (int i = tid; i < 64 * 64; i += 256) {
            int n = i >> 6, k = i & 63;
            Bs[k * 68 + n] = Wcat2[(long long)(tx * 64 + n) * 576 + k0 + k];
        }
        __syncthreads();
        #pragma unroll 8
        for (int kk = 0; kk < 64; ++kk) {
            const float2 a = *(const float2*)&As[kk * 34 + tyt * 2];
            const float4 b = *(const float4*)&Bs[kk * 68 + txt * 4];
            acc[0][0] = fmaf(a.x, b.x, acc[0][0]);
            acc[0][1] = fmaf(a.x, b.y, acc[0][1]);
            acc[0][2] = fmaf(a.x, b.z, acc[0][2]);
            acc[0][3] = fmaf(a.x, b.w, acc[0][3]);
            acc[1][0] = fmaf(a.y, b.x, acc[1][0]);
            acc[1][1] = fmaf(a.y, b.y, acc[1][1]);
            acc[1][2] = fmaf(a.y, b.z, acc[1][2]);
            acc[1][3] = fmaf(a.y, b.w, acc[1][3]);
        }
        __syncthreads();
    }
    float* gt = (float*)smem;            // [32][64] reuse
    #pragma unroll
    for (int i = 0; i < 2; ++i)
        #pragma unroll
        for (int j = 0; j < 4; ++j)
            gt[(tyt * 2 + i) * 64 + txt * 4 + j] = acc[i][j];
    __syncthreads();
    for (int p = tid; p < 512; p += 256) {
        int bl = p >> 4, jl = p & 15;
        int jg = tx * 16 + jl;
        float gr  = gt[bl * 64 + jl * 4 + 0] + bcat2[jg * 4 + 0];
        float gz  = gt[bl * 64 + jl * 4 + 1] + bcat2[jg * 4 + 1];
        float gni = gt[bl * 64 + jl * 4 + 2] + bcat2[jg * 4 + 2];
        float gnh = gt[bl * 64 + jl * 4 + 3] + bcat2[jg * 4 + 3];
        float r = 1.0f / (1.0f + expf(-gr));
        float z = 1.0f / (1.0f + expf(-gz));
        float n = tanhf(gni + r * gnh);
        long long bglob = ty * 32 + bl;
        float hold = Ar[bglob * 576 + 64 + jg];
        float h = (1.0f - z) * n + z * hold;
        Aw[bglob * 576 + 64 + jg] = h;
        hbf[bglob * 512 + jg] = (ushort)bf16_rne(h);
    }
}

// ---- phase L: one 64x128 logits MFMA tile + per-tile row max. job in [0, NJOBS) ----
__device__ __forceinline__ void phaseL(int job,
    const ushort* __restrict__ hbf, const ushort* __restrict__ Wb,
    const float* __restrict__ out_b, float* __restrict__ lbase,
    float* __restrict__ tmaxv, char* smem, float (*s_mv)[2])
{
    const int tid = threadIdx.x;
    const int lane = tid & 63;
    const int wave = tid >> 6;
    const int jy = job / NTILE;
    const int jx = job - jy * NTILE;
    const int row0 = jy * 64;
    const int col0 = jx * 128;
    char* As = smem;
    char* Bs = smem + 8192;
    f32x4 acc[2][4] = {};
    const int srow = tid >> 3;
    const int sch = tid & 7;
    for (int k0 = 0; k0 < 512; k0 += 64) {
        #pragma unroll
        for (int ra = 0; ra < 2; ++ra) {
            int row = ra * 32 + srow;
            const char* g = (const char*)(hbf + (long long)(row0 + row) * 512 + k0) + ((sch ^ (row & 7)) * 16);
            __builtin_amdgcn_global_load_lds(
                (const __attribute__((address_space(1))) void*)g,
                (__attribute__((address_space(3))) void*)(As + row * 128 + sch * 16), 16, 0, 0);
        }
        #pragma unroll
        for (int rb = 0; rb < 4; ++rb) {
            int row = rb * 32 + srow;
            const char* g = (const char*)(Wb + (long long)(col0 + row) * 512 + k0) + ((sch ^ (row & 7)) * 16);
            __builtin_amdgcn_global_load_lds(
                (const __attribute__((address_space(1))) void*)g,
                (__attribute__((address_space(3))) void*)(Bs + row * 128 + sch * 16), 16, 0, 0);
        }
        __syncthreads();
        #pragma unroll
        for (int k32 = 0; k32 < 64; k32 += 32) {
            bf16x8 af[2], bfr[4];
            #pragma unroll
            for (int i = 0; i < 2; ++i) {
                int rA = (wave >> 1) * 32 + i * 16 + (lane & 15);
                int byteA = (rA * 128 + (k32 + ((lane >> 4) << 3)) * 2) ^ ((rA & 7) << 4);
                af[i] = *(const bf16x8*)&As[byteA];
            }
            #pragma unroll
            for (int j = 0; j < 4; ++j) {
                int rB = (wave & 1) * 64 + j * 16 + (lane & 15);
                int byteB = (rB * 128 + (k32 + ((lane >> 4) << 3)) * 2) ^ ((rB & 7) << 4);
                bfr[j] = *(const bf16x8*)&Bs[byteB];
            }
            #pragma unroll
            for (int i = 0; i < 2; ++i)
                #pragma unroll
                for (int j = 0; j < 4; ++j)
                    acc[i][j] = __builtin_amdgcn_mfma_f32_16x16x32_bf16(af[i], bfr[j], acc[i][j], 0, 0, 0);
        }
        __syncthreads();
    }
    const int wm = wave >> 1, wn = wave & 1;
    #pragma unroll
    for (int i = 0; i < 2; ++i) {
        #pragma unroll
        for (int q = 0; q < 4; ++q) {
            int r_local = wm * 32 + i * 16 + ((lane >> 4) << 2) + q;
            long long r = row0 + r_local;
            float* crow = lbase + r * (long long)(SLEN * VOCAB);
            float mv = -INFINITY;
            #pragma unroll
            for (int j = 0; j < 4; ++j) {
                int c = col0 + wn * 64 + j * 16 + (lane & 15);
                float v = acc[i][j][q] + out_b[c];
                crow[c] = v;
                mv = fmaxf(mv, v);
            }
            #pragma unroll
            for (int m = 1; m < 16; m <<= 1) mv = fmaxf(mv, __shfl_xor(mv, m, 64));
            if ((lane & 15) == 0) s_mv[r_local][wn] = mv;
        }
    }
    __syncthreads();
    if (tid < 64)
        tmaxv[(long long)(row0 + tid) * 256 + jx] = fmaxf(s_mv[tid][0], s_mv[tid][1]);
    __syncthreads();
}

// ---- phase A: argmax via tile-maxes + exact fp32 refine + embedding into Aw e-part ----
__device__ __forceinline__ void phaseA(int b, int t,
    const float* __restrict__ lbase, float* __restrict__ Aw,
    const float* __restrict__ out_W, const float* __restrict__ out_b,
    const float* __restrict__ emb, const float* __restrict__ tmaxv,
    float* __restrict__ seq, AmaxSh& sh)
{
    const int tid = threadIdx.x;
    const int lane = tid & 63, wave = tid >> 6;
    const float* row = lbase + (long long)b * (SLEN * (long long)VOCAB);
    float v = (tid < NTILE) ? tmaxv[(long long)b * 256 + tid] : -INFINITY;
    sh.red[tid] = v; __syncthreads();
    for (int s = 128; s > 0; s >>= 1) {
        if (tid < s) sh.red[tid] = fmaxf(sh.red[tid], sh.red[tid + s]);
        __syncthreads();
    }
    float M = sh.red[0];
    if (tid == 0) { sh.cnt2[0] = 0; sh.cnt2[1] = 0; }
    __syncthreads();
    if (tid < NTILE && v >= M - MARGIN) {
        int s = atomicAdd(&sh.cnt2[0], 1);
        if (s < 32) sh.qt[s] = tid;
    }
    __syncthreads();
    int nq = min(sh.cnt2[0], 32);
    for (int idx = tid; idx < nq * 128; idx += 256) {
        int c = sh.qt[idx >> 7] * 128 + (idx & 127);
        if (row[c] >= M - MARGIN) {
            int s = atomicAdd(&sh.cnt2[1], 1);
            if (s < 32) sh.cand[s] = c;
        }
    }
    __syncthreads();
    int nc = min(sh.cnt2[1], 32);
    const float* hrow = Aw + (long long)b * 576 + 64;
    for (int ci = wave; ci < nc; ci += 4) {
        int vv = sh.cand[ci];
        const float* wrow = out_W + (long long)vv * 512;
        float s = 0.f;
        for (int k = lane; k < 512; k += 64) s = fmaf(hrow[k], wrow[k], s);
        for (int off = 32; off > 0; off >>= 1) s += __shfl_down(s, off, 64);
        if (lane == 0) sh.rv[ci] = s + out_b[vv];
    }
    __syncthreads();
    if (tid == 0) {
        float bv = -INFINITY; int sym = 0x7fffffff;
        for (int ci = 0; ci < nc; ++ci) {
            float xx = sh.rv[ci]; int c = sh.cand[ci];
            if (xx > bv || (xx == bv && c < sym)) { bv = xx; sym = c; }
        }
        seq[b * SLEN + t] = (float)sym;
        sh.sym = sym;
    }
    __syncthreads();
    if (tid < EMB) Aw[(long long)b * 576 + tid] = emb[(long long)sh.sym * EMB + tid];
}

// ================= cooperative mega-kernel =================
__global__ __launch_bounds__(256, 2) void mega_kernel(
    const float* __restrict__ Wcat2, const float* __restrict__ bcat2,
    float* __restrict__ AcatA, float* __restrict__ AcatB,
    ushort* __restrict__ hbf, const ushort* __restrict__ Wb,
    const float* __restrict__ out_b, const float* __restrict__ out_W,
    const float* __restrict__ emb, float* __restrict__ seq,
    float* __restrict__ logits_all, float* __restrict__ tmaxv)
{
    cg::grid_group gg = cg::this_grid();
    __shared__ __align__(16) char smem[26624];
    __shared__ float s_mv[64][2];
    __shared__ AmaxSh sh;

    for (int t = 0; t < SLEN; ++t) {
        const float* Ar = (t & 1) ? AcatB : AcatA;
        float*       Aw = (t & 1) ? AcatA : AcatB;
        float* lbase = logits_all + (long long)t * VOCAB;

        if (blockIdx.x < 256) phaseG(blockIdx.x, Ar, Aw, Wcat2, bcat2, hbf, smem);
        __threadfence();
        gg.sync();
        __threadfence();

        for (int job = blockIdx.x; job < NJOBS; job += gridDim.x)
            phaseL(job, hbf, Wb, out_b, lbase, tmaxv, smem, s_mv);
        __threadfence();
        gg.sync();
        __threadfence();

        if (blockIdx.x < BATCH) phaseA(blockIdx.x, t, lbase, Aw, out_W, out_b, emb, tmaxv, seq, sh);
        __threadfence();
        gg.sync();
        __threadfence();
    }
}

// ================= fallback kernels (round-3-style, bit-identical math) =================
__global__ void gates_fb_kernel(const float* __restrict__ gcat, const float* __restrict__ Ar,
                                float* __restrict__ Aw, const float* __restrict__ bcat2,
                                ushort* __restrict__ hbf) {
    int idx = blockIdx.x * 256 + threadIdx.x;   // b*512 + j
    int b = idx >> 9, j = idx & 511;
    const float* g = gcat + (long long)b * 2048 + j * 4;
    float r = 1.0f / (1.0f + expf(-(g[0] + bcat2[j * 4 + 0])));
    float z = 1.0f / (1.0f + expf(-(g[1] + bcat2[j * 4 + 1])));
    float n = tanhf((g[2] + bcat2[j * 4 + 2]) + r * (g[3] + bcat2[j * 4 + 3]));
    float hold = Ar[(long long)b * 576 + 64 + j];
    float h = (1.0f - z) * n + z * hold;
    Aw[(long long)b * 576 + 64 + j] = h;
    hbf[idx] = (ushort)bf16_rne(h);
}

__global__ __launch_bounds__(256) void logits_fb_kernel(
    const ushort* __restrict__ hbf, const ushort* __restrict__ Wb,
    const float* __restrict__ out_b, float* __restrict__ lbase, float* __restrict__ tmaxv) {
    __shared__ __align__(16) char smem[24576];
    __shared__ float s_mv[64][2];
    phaseL(blockIdx.x, hbf, Wb, out_b, lbase, tmaxv, smem, s_mv);
}

__global__ void argmax_fb_kernel(const float* __restrict__ tmaxv, float* __restrict__ lbase,
                                 float* __restrict__ Aw, const float* __restrict__ out_W,
                                 const float* __restrict__ out_b, const float* __restrict__ emb,
                                 float* __restrict__ seq, int t) {
    __shared__ AmaxSh sh;
    phaseA(blockIdx.x, t, lbase, Aw, out_W, out_b, emb, tmaxv, seq, sh);
}

extern "C" void kernel_launch(void* const* d_in, const int* in_sizes, int n_in,
                              void* d_out, int out_size, void* d_ws, size_t ws_size,
                              hipStream_t stream) {
    const float* x     = (const float*)d_in[0];
    const float* enc_W = (const float*)d_in[1];
    const float* enc_b = (const float*)d_in[2];
    const float* in_W  = (const float*)d_in[3];
    const float* in_b  = (const float*)d_in[4];
    const float* W_ih  = (const float*)d_in[5];
    const float* W_hh  = (const float*)d_in[6];
    const float* b_ih  = (const float*)d_in[7];
    const float* b_hh  = (const float*)d_in[8];
    const float* out_W = (const float*)d_in[9];
    const float* out_b = (const float*)d_in[10];
    const float* emb   = (const float*)d_in[11];
    const float* sos   = (const float*)d_in[12];

    float* seq    = (float*)d_out;
    float* logits = (float*)d_out + BATCH * SLEN;

    char* p = (char*)d_ws;
    ushort* Wb    = (ushort*)p;  p += (size_t)VOCAB * HSZ * 2;
    float* Wcat2  = (float*)p;   p += (size_t)2048 * 576 * 4;
    float* bcat2  = (float*)p;   p += 2048 * 4;
    float* AcatA  = (float*)p;   p += (size_t)BATCH * 576 * 4;
    float* AcatB  = (float*)p;   p += (size_t)BATCH * 576 * 4;
    ushort* hbf   = (ushort*)p;  p += (size_t)BATCH * HSZ * 2;
    float* feat   = (float*)p;   p += (size_t)BATCH * DFEAT * 4;
    float* tmaxv  = (float*)p;   p += (size_t)BATCH * 256 * 4;
    float* gcat   = (float*)p;   p += (size_t)BATCH * 2048 * 4;   // fallback only

    // prologue
    prep_kernel<<<1024, 256, 0, stream>>>(out_W, Wb, W_ih, W_hh, b_ih, b_hh,
                                          Wcat2, bcat2, sos, AcatA);
    gemm_atb<64, 64, 32, 4, 4><<<dim3(DFEAT / 64, BATCH / 64), 256, 0, stream>>>(
        x, enc_W, enc_b, feat, DFEAT, BATCH, DFEAT, DIN);
    gemm_atb<64, 64, 32, 4, 4><<<dim3(HSZ / 64, BATCH / 64), 256, 0, stream>>>(
        feat, in_W, in_b, AcatA + 64, 576, BATCH, HSZ, DFEAT);

    // try cooperative mega-kernel; fall back to per-step kernels on ANY failure
    int nb = 0;
    hipError_t qerr = hipOccupancyMaxActiveBlocksPerMultiprocessor(
        &nb, reinterpret_cast<const void*>(mega_kernel), 256, 0);
    hipError_t lerr = hipErrorUnknown;
    if (qerr == hipSuccess && nb >= 1) {
        int grid = (nb >= 2) ? 512 : 256;
        void* kargs[] = {
            (void*)&Wcat2, (void*)&bcat2, (void*)&AcatA, (void*)&AcatB,
            (void*)&hbf, (void*)&Wb, (void*)&out_b, (void*)&out_W,
            (void*)&emb, (void*)&seq, (void*)&logits, (void*)&tmaxv
        };
        lerr = hipLaunchCooperativeKernel((void*)mega_kernel, dim3(grid), dim3(256),
                                          kargs, 0, stream);
    }
    if (lerr != hipSuccess) {
        for (int t = 0; t < SLEN; ++t) {
            const float* Ar = (t & 1) ? AcatB : AcatA;
            float*       Aw = (t & 1) ? AcatA : AcatB;
            float* lbase = logits + (long long)t * VOCAB;
            gemm_atb<64, 64, 32, 4, 4><<<dim3(2048 / 64, BATCH / 64), 256, 0, stream>>>(
                Ar, Wcat2, nullptr, gcat, 2048, BATCH, 2048, 576);
            gates_fb_kernel<<<BATCH * HSZ / 256, 256, 0, stream>>>(gcat, Ar, Aw, bcat2, hbf);
            logits_fb_kernel<<<NJOBS, 256, 0, stream>>>(hbf, Wb, out_b, lbase, tmaxv);
            argmax_fb_kernel<<<BATCH, 256, 0, stream>>>(tmaxv, lbase, Aw, out_W, out_b, emb, seq, t);
        }
    }
}

// Round 6
// 1514.828 us; speedup vs baseline: 3.4231x; 3.4231x over previous
//
#include <hip/hip_runtime.h>
#include <math.h>

#define BATCH 256
#define DIN 512
#define DFEAT 512
#define HSZ 512
#define VOCAB 32000
#define EMB 64
#define SLEN 16
#define NTILE 500          // VOCAB / 64 col-tiles
#define MARGIN 0.0625f

typedef __attribute__((ext_vector_type(8))) short bf16x8;
typedef __attribute__((ext_vector_type(4))) float f32x4;

__device__ inline unsigned bf16_rne(float x) {
    union { float f; unsigned u; } u; u.f = x;
    unsigned r = u.u + 0x7fff + ((u.u >> 16) & 1);
    return r >> 16;
}

// ---------- fp32 SMEM GEMM (prologue): C = A @ W^T (+bias) ----------
template<int BM, int BN, int BK, int TM, int TN>
__global__ __launch_bounds__(256) void gemm_atb(
    const float* __restrict__ A,
    const float* __restrict__ W,
    const float* __restrict__ bias,
    float* __restrict__ C, long long ldc,
    int M, int N, int K)
{
    __shared__ float As[BK][BM + 4];
    __shared__ float Bs[BK][BN + 4];
    constexpr int THREADS = (BM / TM) * (BN / TN);
    const int tid = threadIdx.x;
    const int tx = tid % (BN / TN);
    const int ty = tid / (BN / TN);
    const int row0 = blockIdx.y * BM;
    const int col0 = blockIdx.x * BN;
    float acc[TM][TN] = {};
    for (int k0 = 0; k0 < K; k0 += BK) {
        for (int i = tid; i < BM * BK; i += THREADS) {
            int m = i / BK, k = i % BK;
            As[k][m] = A[(long long)(row0 + m) * K + k0 + k];
        }
        for (int i = tid; i < BN * BK; i += THREADS) {
            int n = i / BK, k = i % BK;
            Bs[k][n] = W[(long long)(col0 + n) * K + k0 + k];
        }
        __syncthreads();
        #pragma unroll
        for (int kk = 0; kk < BK; ++kk) {
            float a[TM], b[TN];
            #pragma unroll
            for (int i = 0; i < TM; ++i) a[i] = As[kk][ty * TM + i];
            #pragma unroll
            for (int j = 0; j < TN; ++j) b[j] = Bs[kk][tx * TN + j];
            #pragma unroll
            for (int i = 0; i < TM; ++i)
                #pragma unroll
                for (int j = 0; j < TN; ++j)
                    acc[i][j] = fmaf(a[i], b[j], acc[i][j]);
        }
        __syncthreads();
    }
    #pragma unroll
    for (int i = 0; i < TM; ++i) {
        long long m = row0 + ty * TM + i;
        float* crow = C + m * ldc;
        #pragma unroll
        for (int j = 0; j < TN; ++j) {
            int n = col0 + tx * TN + j;
            float v = acc[i][j];
            if (bias) v += bias[n];
            crow[n] = v;
        }
    }
}

// ---------- fused prologue: Wb cast, Wcat2/bcat2 build (interleaved j*4+comp), sos -> AcatA ----------
__global__ void prep_kernel(const float* __restrict__ out_W, ushort* __restrict__ Wb,
                            const float* __restrict__ W_ih, const float* __restrict__ W_hh,
                            const float* __restrict__ b_ih, const float* __restrict__ b_hh,
                            float* __restrict__ Wcat2, float* __restrict__ bcat2,
                            const float* __restrict__ sos, float* __restrict__ AcatA)
{
    const int stride = gridDim.x * 256;
    const int t0 = blockIdx.x * 256 + threadIdx.x;
    for (int i = t0; i < VOCAB * HSZ / 4; i += stride) {
        const float4 v = ((const float4*)out_W)[i];
        ushort4 o;
        o.x = (ushort)bf16_rne(v.x); o.y = (ushort)bf16_rne(v.y);
        o.z = (ushort)bf16_rne(v.z); o.w = (ushort)bf16_rne(v.w);
        ((ushort4*)Wb)[i] = o;
    }
    for (long long i = t0; i < 2048LL * 576; i += stride) {
        int g = (int)(i / 576), k = (int)(i % 576);
        int j = g >> 2, comp = g & 3;
        float v;
        if (comp == 0)      v = (k < 64) ? W_ih[j * 64 + k]          : W_hh[(long long)j * 512 + k - 64];
        else if (comp == 1) v = (k < 64) ? W_ih[(512 + j) * 64 + k]  : W_hh[(long long)(512 + j) * 512 + k - 64];
        else if (comp == 2) v = (k < 64) ? W_ih[(1024 + j) * 64 + k] : 0.f;
        else                v = (k < 64) ? 0.f                        : W_hh[(long long)(1024 + j) * 512 + k - 64];
        Wcat2[i] = v;
    }
    for (int i = t0; i < 2048; i += stride) {
        int j = i >> 2, comp = i & 3;
        float bv = (comp == 0) ? b_ih[j] + b_hh[j]
                 : (comp == 1) ? b_ih[512 + j] + b_hh[512 + j]
                 : (comp == 2) ? b_ih[1024 + j] : b_hh[1024 + j];
        bcat2[i] = bv;
    }
    for (int i = t0; i < BATCH * EMB; i += stride) {
        AcatA[(long long)(i >> 6) * 576 + (i & 63)] = sos[i & 63];
    }
}

// ---------- G: fused gcat GEMM (LDS) + GRU gates. 256 blocks x 256 thr ----------
__global__ __launch_bounds__(256) void gru_fused_kernel(
    const float* __restrict__ Ar, float* __restrict__ Aw,
    const float* __restrict__ Wcat2, const float* __restrict__ bcat2,
    ushort* __restrict__ hbf)
{
    __shared__ __align__(16) char smem[26624];
    const int tid = threadIdx.x;
    const int blk = blockIdx.x;
    const int ty = blk >> 5;            // batch group (32 rows)
    const int tx = blk & 31;            // col group (64 interleaved cols = 16 j)
    float* As = (float*)smem;                    // [64][34]
    float* Bs = (float*)(smem + 8704);           // [64][68]
    const int tyt = tid >> 4;           // 2 batch rows
    const int txt = tid & 15;           // 4 cols
    float acc[2][4] = {};
    for (int k0 = 0; k0 < 576; k0 += 64) {
        for (int i = tid; i < 32 * 64; i += 256) {
            int m = i >> 6, k = i & 63;
            As[k * 34 + m] = Ar[(long long)(ty * 32 + m) * 576 + k0 + k];
        }
        for (int i = tid; i < 64 * 64; i += 256) {
            int n = i >> 6, k = i & 63;
            Bs[k * 68 + n] = Wcat2[(long long)(tx * 64 + n) * 576 + k0 + k];
        }
        __syncthreads();
        #pragma unroll 8
        for (int kk = 0; kk < 64; ++kk) {
            const float2 a = *(const float2*)&As[kk * 34 + tyt * 2];
            const float4 b = *(const float4*)&Bs[kk * 68 + txt * 4];
            acc[0][0] = fmaf(a.x, b.x, acc[0][0]);
            acc[0][1] = fmaf(a.x, b.y, acc[0][1]);
            acc[0][2] = fmaf(a.x, b.z, acc[0][2]);
            acc[0][3] = fmaf(a.x, b.w, acc[0][3]);
            acc[1][0] = fmaf(a.y, b.x, acc[1][0]);
            acc[1][1] = fmaf(a.y, b.y, acc[1][1]);
            acc[1][2] = fmaf(a.y, b.z, acc[1][2]);
            acc[1][3] = fmaf(a.y, b.w, acc[1][3]);
        }
        __syncthreads();
    }
    float* gt = (float*)smem;            // [32][64] reuse
    #pragma unroll
    for (int i = 0; i < 2; ++i)
        #pragma unroll
        for (int j = 0; j < 4; ++j)
            gt[(tyt * 2 + i) * 64 + txt * 4 + j] = acc[i][j];
    __syncthreads();
    for (int p = tid; p < 512; p += 256) {
        int bl = p >> 4, jl = p & 15;
        int jg = tx * 16 + jl;
        float gr  = gt[bl * 64 + jl * 4 + 0] + bcat2[jg * 4 + 0];
        float gz  = gt[bl * 64 + jl * 4 + 1] + bcat2[jg * 4 + 1];
        float gni = gt[bl * 64 + jl * 4 + 2] + bcat2[jg * 4 + 2];
        float gnh = gt[bl * 64 + jl * 4 + 3] + bcat2[jg * 4 + 3];
        float r = 1.0f / (1.0f + expf(-gr));
        float z = 1.0f / (1.0f + expf(-gz));
        float n = tanhf(gni + r * gnh);
        long long bglob = ty * 32 + bl;
        float hold = Ar[bglob * 576 + 64 + jg];
        float h = (1.0f - z) * n + z * hold;
        Aw[bglob * 576 + 64 + jg] = h;
        hbf[bglob * 512 + jg] = (ushort)bf16_rne(h);
    }
}

// ---------- L: logits MFMA, BM=256 (all batch) x BN=64 cols, 500 blocks ----------
// Wb read exactly once per step; hbf (256KB) L2-hot.
__global__ __launch_bounds__(256) void logits_bm256_kernel(
    const ushort* __restrict__ hbf,   // [256][512] bf16
    const ushort* __restrict__ Wb,    // [VOCAB][512] bf16
    const float* __restrict__ out_b,
    float* __restrict__ lbase, float* __restrict__ tmaxv)
{
    __shared__ __align__(16) char As[32768];   // 256 x 64 bf16, XOR-swizzled rows
    __shared__ __align__(16) char Bs[8192];    // 64 x 64 bf16
    __shared__ float s_mv[256];
    const int tid = threadIdx.x;
    const int lane = tid & 63;
    const int wave = tid >> 6;        // wm: owns rows wave*64..+63
    const int jx = blockIdx.x;
    const int col0 = jx * 64;

    f32x4 acc[4][4] = {};
    const int srow = tid >> 3;        // 0..31
    const int sch = tid & 7;

    for (int k0 = 0; k0 < 512; k0 += 64) {
        #pragma unroll
        for (int ra = 0; ra < 8; ++ra) {
            int row = ra * 32 + srow;
            const char* g = (const char*)(hbf + (long long)row * 512 + k0) + ((sch ^ (row & 7)) * 16);
            __builtin_amdgcn_global_load_lds(
                (const __attribute__((address_space(1))) void*)g,
                (__attribute__((address_space(3))) void*)(As + row * 128 + sch * 16), 16, 0, 0);
        }
        #pragma unroll
        for (int rb = 0; rb < 2; ++rb) {
            int row = rb * 32 + srow;
            const char* g = (const char*)(Wb + (long long)(col0 + row) * 512 + k0) + ((sch ^ (row & 7)) * 16);
            __builtin_amdgcn_global_load_lds(
                (const __attribute__((address_space(1))) void*)g,
                (__attribute__((address_space(3))) void*)(Bs + row * 128 + sch * 16), 16, 0, 0);
        }
        __syncthreads();
        #pragma unroll
        for (int k32 = 0; k32 < 64; k32 += 32) {
            bf16x8 af[4], bfr[4];
            #pragma unroll
            for (int f = 0; f < 4; ++f) {
                int rA = wave * 64 + f * 16 + (lane & 15);
                int byteA = (rA * 128 + (k32 + ((lane >> 4) << 3)) * 2) ^ ((rA & 7) << 4);
                af[f] = *(const bf16x8*)&As[byteA];
            }
            #pragma unroll
            for (int j = 0; j < 4; ++j) {
                int rB = j * 16 + (lane & 15);
                int byteB = (rB * 128 + (k32 + ((lane >> 4) << 3)) * 2) ^ ((rB & 7) << 4);
                bfr[j] = *(const bf16x8*)&Bs[byteB];
            }
            #pragma unroll
            for (int f = 0; f < 4; ++f)
                #pragma unroll
                for (int j = 0; j < 4; ++j)
                    acc[f][j] = __builtin_amdgcn_mfma_f32_16x16x32_bf16(af[f], bfr[j], acc[f][j], 0, 0, 0);
        }
        __syncthreads();
    }

    // epilogue: bias + store + per-row max over this 64-col tile
    #pragma unroll
    for (int f = 0; f < 4; ++f) {
        #pragma unroll
        for (int q = 0; q < 4; ++q) {
            int r_local = wave * 64 + f * 16 + ((lane >> 4) << 2) + q;
            float* crow = lbase + (long long)r_local * (SLEN * (long long)VOCAB);
            float mv = -INFINITY;
            #pragma unroll
            for (int j = 0; j < 4; ++j) {
                int c = col0 + j * 16 + (lane & 15);
                float v = acc[f][j][q] + out_b[c];
                crow[c] = v;
                mv = fmaxf(mv, v);
            }
            #pragma unroll
            for (int m = 1; m < 16; m <<= 1) mv = fmaxf(mv, __shfl_xor(mv, m, 64));
            if ((lane & 15) == 0) s_mv[r_local] = mv;
        }
    }
    __syncthreads();
    tmaxv[(long long)tid * 512 + jx] = s_mv[tid];
}

// ---------- A: argmax via tile-maxes + exact fp32 refine + embedding into Aw ----------
__global__ __launch_bounds__(256) void argmax_kernel(
    const float* __restrict__ tmaxv, const float* __restrict__ lbase,
    float* __restrict__ Aw, const float* __restrict__ out_W,
    const float* __restrict__ out_b, const float* __restrict__ emb,
    float* __restrict__ seq, int t)
{
    __shared__ float s_red[256];
    __shared__ int s_qt[32];
    __shared__ int s_cand[32];
    __shared__ float s_rv[32];
    __shared__ int s_cnt2[2];
    __shared__ int s_sym;
    const int b = blockIdx.x;
    const int tid = threadIdx.x;
    const int lane = tid & 63, wave = tid >> 6;
    const float* row = lbase + (long long)b * (SLEN * (long long)VOCAB);

    float v0 = tmaxv[(long long)b * 512 + tid];
    float v1 = (tid + 256 < NTILE) ? tmaxv[(long long)b * 512 + 256 + tid] : -INFINITY;
    s_red[tid] = fmaxf(v0, v1); __syncthreads();
    for (int s = 128; s > 0; s >>= 1) {
        if (tid < s) s_red[tid] = fmaxf(s_red[tid], s_red[tid + s]);
        __syncthreads();
    }
    float M = s_red[0];
    if (tid == 0) { s_cnt2[0] = 0; s_cnt2[1] = 0; }
    __syncthreads();
    if (v0 >= M - MARGIN) {
        int s = atomicAdd(&s_cnt2[0], 1);
        if (s < 32) s_qt[s] = tid;
    }
    if (v1 >= M - MARGIN) {
        int s = atomicAdd(&s_cnt2[0], 1);
        if (s < 32) s_qt[s] = tid + 256;
    }
    __syncthreads();
    int nq = min(s_cnt2[0], 32);
    for (int idx = tid; idx < nq * 64; idx += 256) {
        int c = s_qt[idx >> 6] * 64 + (idx & 63);
        if (row[c] >= M - MARGIN) {
            int s = atomicAdd(&s_cnt2[1], 1);
            if (s < 32) s_cand[s] = c;
        }
    }
    __syncthreads();
    int nc = min(s_cnt2[1], 32);
    const float* hrow = Aw + (long long)b * 576 + 64;
    for (int ci = wave; ci < nc; ci += 4) {
        int vv = s_cand[ci];
        const float* wrow = out_W + (long long)vv * 512;
        float s = 0.f;
        for (int k = lane; k < 512; k += 64) s = fmaf(hrow[k], wrow[k], s);
        for (int off = 32; off > 0; off >>= 1) s += __shfl_down(s, off, 64);
        if (lane == 0) s_rv[ci] = s + out_b[vv];
    }
    __syncthreads();
    if (tid == 0) {
        float bv = -INFINITY; int sym = 0x7fffffff;
        for (int ci = 0; ci < nc; ++ci) {
            float xx = s_rv[ci]; int c = s_cand[ci];
            if (xx > bv || (xx == bv && c < sym)) { bv = xx; sym = c; }
        }
        seq[b * SLEN + t] = (float)sym;
        s_sym = sym;
    }
    __syncthreads();
    if (tid < EMB) Aw[(long long)b * 576 + tid] = emb[(long long)s_sym * EMB + tid];
}

extern "C" void kernel_launch(void* const* d_in, const int* in_sizes, int n_in,
                              void* d_out, int out_size, void* d_ws, size_t ws_size,
                              hipStream_t stream) {
    const float* x     = (const float*)d_in[0];
    const float* enc_W = (const float*)d_in[1];
    const float* enc_b = (const float*)d_in[2];
    const float* in_W  = (const float*)d_in[3];
    const float* in_b  = (const float*)d_in[4];
    const float* W_ih  = (const float*)d_in[5];
    const float* W_hh  = (const float*)d_in[6];
    const float* b_ih  = (const float*)d_in[7];
    const float* b_hh  = (const float*)d_in[8];
    const float* out_W = (const float*)d_in[9];
    const float* out_b = (const float*)d_in[10];
    const float* emb   = (const float*)d_in[11];
    const float* sos   = (const float*)d_in[12];

    float* seq    = (float*)d_out;
    float* logits = (float*)d_out + BATCH * SLEN;

    char* p = (char*)d_ws;
    ushort* Wb    = (ushort*)p;  p += (size_t)VOCAB * HSZ * 2;
    float* Wcat2  = (float*)p;   p += (size_t)2048 * 576 * 4;
    float* bcat2  = (float*)p;   p += 2048 * 4;
    float* AcatA  = (float*)p;   p += (size_t)BATCH * 576 * 4;
    float* AcatB  = (float*)p;   p += (size_t)BATCH * 576 * 4;
    ushort* hbf   = (ushort*)p;  p += (size_t)BATCH * HSZ * 2;
    float* feat   = (float*)p;   p += (size_t)BATCH * DFEAT * 4;
    float* tmaxv  = (float*)p;   p += (size_t)BATCH * 512 * 4;

    // prologue
    prep_kernel<<<1024, 256, 0, stream>>>(out_W, Wb, W_ih, W_hh, b_ih, b_hh,
                                          Wcat2, bcat2, sos, AcatA);
    gemm_atb<64, 64, 32, 4, 4><<<dim3(DFEAT / 64, BATCH / 64), 256, 0, stream>>>(
        x, enc_W, enc_b, feat, DFEAT, BATCH, DFEAT, DIN);
    gemm_atb<64, 64, 32, 4, 4><<<dim3(HSZ / 64, BATCH / 64), 256, 0, stream>>>(
        feat, in_W, in_b, AcatA + 64, 576, BATCH, HSZ, DFEAT);

    for (int t = 0; t < SLEN; ++t) {
        const float* Ar = (t & 1) ? AcatB : AcatA;
        float*       Aw = (t & 1) ? AcatA : AcatB;
        float* lbase = logits + (long long)t * VOCAB;
        gru_fused_kernel<<<256, 256, 0, stream>>>(Ar, Aw, Wcat2, bcat2, hbf);
        logits_bm256_kernel<<<NTILE, 256, 0, stream>>>(hbf, Wb, out_b, lbase, tmaxv);
        argmax_kernel<<<BATCH, 256, 0, stream>>>(tmaxv, lbase, Aw, out_W, out_b, emb, seq, t);
    }
}